// Round 6
// baseline (106.259 us; speedup 1.0000x reference)
//
#include <hip/hip_runtime.h>
#include <math.h>

#define N_ 32
#define C_ 256
#define H_ 56
#define W_ 56
#define HW_ (H_*W_)          // 3136
#define HW4_ (HW_/4)         // 784
#define CHW_ (C_*HW_)        // 802816
#define NHW_ (N_*HW_)        // 100352
#define NCW_ (N_*C_*W_)      // 458752
#define NHC_ (N_*H_*C_)      // 458752
#define BN_EPS_ 1e-5f

#define NB_CP 392            // C-pool blocks (dispatched FIRST)
#define NB_PL 2048           // plane blocks: 4 planes (1/wave) each

// ---- fused pools ----
// blocks [0, NB_CP): C-pool, 4-way c-split deep chain + LDS combine
// blocks [NB_CP, NB_CP+NB_PL): wave = one (n,c) plane, register-only reductions
__global__ __launch_bounds__(256) void pools_k(
        const float* __restrict__ x,
        float* __restrict__ maxC, float* __restrict__ meanC,
        float* __restrict__ maxH, float* __restrict__ meanH,
        float* __restrict__ maxW, float* __restrict__ meanW,
        float* __restrict__ y) {
    __shared__ float4 smx[4][64];
    __shared__ float4 ssm[4][64];
    int b = blockIdx.x;
    int tid = threadIdx.x;
    int wave = tid >> 6, lane = tid & 63;
    const float4* x4 = (const float4*)x;
    if (b < NB_CP) {
        // ---- C-pool: output float4 q over [N, HW4]; wave = c-group of 64 ----
        int q = b * 64 + lane;                     // 0..NHW/4-1
        int n = q / HW4_;
        int hw4 = q - n * HW4_;
        size_t base = (size_t)n * (CHW_ / 4) + hw4 + (size_t)(wave * 64) * HW4_;
        float4 mx = make_float4(-INFINITY, -INFINITY, -INFINITY, -INFINITY);
        float4 sm = make_float4(0.f, 0.f, 0.f, 0.f);
        #pragma unroll 16
        for (int i = 0; i < 64; ++i) {
            float4 v = x4[base + (size_t)i * HW4_];
            mx.x = fmaxf(mx.x, v.x); mx.y = fmaxf(mx.y, v.y);
            mx.z = fmaxf(mx.z, v.z); mx.w = fmaxf(mx.w, v.w);
            sm.x += v.x; sm.y += v.y; sm.z += v.z; sm.w += v.w;
        }
        smx[wave][lane] = mx;
        ssm[wave][lane] = sm;
        __syncthreads();
        if (tid < 64) {
            float4 m = smx[0][tid];
            #pragma unroll
            for (int j = 1; j < 4; ++j) {
                float4 v = smx[j][tid];
                m.x = fmaxf(m.x, v.x); m.y = fmaxf(m.y, v.y);
                m.z = fmaxf(m.z, v.z); m.w = fmaxf(m.w, v.w);
            }
            ((float4*)maxC)[b * 64 + tid] = m;
        } else if (tid < 128) {
            int t2 = tid - 64;
            float4 s = ssm[0][t2];
            #pragma unroll
            for (int j = 1; j < 4; ++j) {
                float4 v = ssm[j][t2];
                s.x += v.x; s.y += v.y; s.z += v.z; s.w += v.w;
            }
            s.x *= (1.f / C_); s.y *= (1.f / C_); s.z *= (1.f / C_); s.w *= (1.f / C_);
            ((float4*)meanC)[b * 64 + t2] = s;
        }
    } else {
        // ---- plane wave: register-only H/W/global pooling ----
        int pb = (b - NB_CP) * 4 + wave;           // plane id 0..8191
        int n = pb >> 8, c = pb & 255;
        size_t pbase = (size_t)pb * HW4_;
        int g = lane >> 4, q = lane & 15;
        bool act = q < 14;
        float4 v[14];
        size_t base = pbase + g * 14 + q;
        // prefetch entire plane into registers: rows 4t+g, 14 float4 each
        #pragma unroll
        for (int t = 0; t < 14; ++t) {
            if (act) v[t] = x4[base + 56 * t];
        }
        // column stats (per-lane float4 over its rows)
        float4 cmx = make_float4(-INFINITY, -INFINITY, -INFINITY, -INFINITY);
        float4 csm = make_float4(0.f, 0.f, 0.f, 0.f);
        #pragma unroll
        for (int t = 0; t < 14; ++t) {
            cmx.x = fmaxf(cmx.x, v[t].x); cmx.y = fmaxf(cmx.y, v[t].y);
            cmx.z = fmaxf(cmx.z, v[t].z); cmx.w = fmaxf(cmx.w, v[t].w);
            csm.x += v[t].x; csm.y += v[t].y; csm.z += v[t].z; csm.w += v[t].w;
        }
        // row stats: per t, reduce across q within the 16-lane group
        #pragma unroll
        for (int t = 0; t < 14; ++t) {
            float rmx = act ? fmaxf(fmaxf(v[t].x, v[t].y), fmaxf(v[t].z, v[t].w))
                            : -INFINITY;
            float rsm = act ? (v[t].x + v[t].y + v[t].z + v[t].w) : 0.f;
            #pragma unroll
            for (int off = 8; off >= 1; off >>= 1) {
                rmx = fmaxf(rmx, __shfl_xor(rmx, off));
                rsm += __shfl_xor(rsm, off);
            }
            if (q == 0) {
                int h = 4 * t + g;
                int o = (n * H_ + h) * C_ + c;
                maxW[o] = rmx;
                meanW[o] = rsm * (1.f / W_);
            }
        }
        // combine column stats across g (xor 16, 32)
        #pragma unroll
        for (int off = 16; off <= 32; off <<= 1) {
            cmx.x = fmaxf(cmx.x, __shfl_xor(cmx.x, off));
            cmx.y = fmaxf(cmx.y, __shfl_xor(cmx.y, off));
            cmx.z = fmaxf(cmx.z, __shfl_xor(cmx.z, off));
            cmx.w = fmaxf(cmx.w, __shfl_xor(cmx.w, off));
            csm.x += __shfl_xor(csm.x, off);
            csm.y += __shfl_xor(csm.y, off);
            csm.z += __shfl_xor(csm.z, off);
            csm.w += __shfl_xor(csm.w, off);
        }
        if (g == 0 && act) {
            ((float4*)maxH)[(n * C_ + c) * 14 + q] = cmx;
            float4 mh = make_float4(csm.x * (1.f / H_), csm.y * (1.f / H_),
                                    csm.z * (1.f / H_), csm.w * (1.f / H_));
            ((float4*)meanH)[(n * C_ + c) * 14 + q] = mh;
        }
        // global mean y[n,c]
        float sq = act ? (csm.x + csm.y + csm.z + csm.w) : 0.f;
        #pragma unroll
        for (int off = 8; off >= 1; off >>= 1) sq += __shfl_xor(sq, off);
        if (lane == 0) y[n * C_ + c] = sq * (1.f / HW_);
    }
}

// ---- conv 7x7 + BN + sigmoid, compile-time geometry ----
template <int R, int Cc>
__device__ __forceinline__ void conv7_part(int t, const float* __restrict__ p0,
                                           const float* __restrict__ p1,
                                           const float* __restrict__ wt,
                                           float g, float bb, float m, float v,
                                           float* __restrict__ out) {
    const int per = R * Cc;
    int n = t / per;
    int r2 = t - n * per;
    int i = r2 / Cc, j = r2 - i * Cc;
    const float* b0 = p0 + (size_t)n * per;
    const float* b1 = p1 + (size_t)n * per;
    float acc = 0.f;
    #pragma unroll
    for (int ki = 0; ki < 7; ++ki) {
        int ii = i + ki - 3;
        if (ii < 0 || ii >= R) continue;
        #pragma unroll
        for (int kj = 0; kj < 7; ++kj) {
            int jj = j + kj - 3;
            if (jj < 0 || jj >= Cc) continue;
            int idx = ii * Cc + jj;
            acc += b0[idx] * wt[ki * 7 + kj] + b1[idx] * wt[49 + ki * 7 + kj];
        }
    }
    float o = (acc - m) * rsqrtf(v + BN_EPS_) * g + bb;
    out[t] = 1.f / (1.f + expf(-o));
}

#define NB_SS (NHW_ / 256)            // 392
#define NB_SH (NCW_ / 256)            // 1792
#define NB_SW (NHC_ / 256)            // 1792

// ---- fused: 3 gate convs + ECA sort/conv/unsort ----
__global__ __launch_bounds__(256) void conv_eca_k(
        const float* __restrict__ maxC, const float* __restrict__ meanC,
        const float* __restrict__ maxH, const float* __restrict__ meanH,
        const float* __restrict__ maxW, const float* __restrict__ meanW,
        const float* __restrict__ w_s, const float* __restrict__ g_s,
        const float* __restrict__ b_s, const float* __restrict__ m_s,
        const float* __restrict__ v_s,
        const float* __restrict__ w_h, const float* __restrict__ g_h,
        const float* __restrict__ b_h, const float* __restrict__ m_h,
        const float* __restrict__ v_h,
        const float* __restrict__ w_w, const float* __restrict__ g_w,
        const float* __restrict__ b_w, const float* __restrict__ m_w,
        const float* __restrict__ v_w,
        const float* __restrict__ y, const float* __restrict__ w_eca,
        float* __restrict__ s_s, float* __restrict__ s_h, float* __restrict__ s_w,
        float* __restrict__ gate) {
    __shared__ float sv[C_];
    __shared__ int si[C_];
    int b = blockIdx.x;
    int tid = threadIdx.x;
    if (b < NB_SS) {
        conv7_part<H_, W_>(b * 256 + tid, maxC, meanC, w_s, g_s[0], b_s[0], m_s[0],
                           v_s[0], s_s);
    } else if (b < NB_SS + NB_SH) {
        conv7_part<C_, W_>((b - NB_SS) * 256 + tid, maxH, meanH, w_h, g_h[0], b_h[0],
                           m_h[0], v_h[0], s_h);
    } else if (b < NB_SS + NB_SH + NB_SW) {
        conv7_part<H_, C_>((b - NB_SS - NB_SH) * 256 + tid, maxW, meanW, w_w, g_w[0],
                           b_w[0], m_w[0], v_w[0], s_w);
    } else {
        int n = b - (NB_SS + NB_SH + NB_SW);
        sv[tid] = y[n * C_ + tid];
        si[tid] = tid;
        __syncthreads();
        for (int k = 2; k <= C_; k <<= 1) {
            for (int j = k >> 1; j > 0; j >>= 1) {
                int ixj = tid ^ j;
                if (ixj > tid) {
                    float v1 = sv[tid], v2 = sv[ixj];
                    int i1 = si[tid], i2 = si[ixj];
                    bool before = (v1 > v2) || (v1 == v2 && i1 < i2);
                    bool dir = ((tid & k) == 0);
                    if (dir ? !before : before) {
                        sv[tid] = v2; sv[ixj] = v1;
                        si[tid] = i2; si[ixj] = i1;
                    }
                }
                __syncthreads();
            }
        }
        float o = 0.f;
        #pragma unroll
        for (int j = 0; j < 5; ++j) {
            int p = tid + j - 2;
            if (p >= 0 && p < C_) o += sv[p] * w_eca[j];
        }
        gate[n * C_ + si[tid]] = 1.f / (1.f + expf(-o));
    }
}

// ---- final apply: 2 float4 per thread for load depth ----
__global__ __launch_bounds__(256) void apply_k(
        const float* __restrict__ x, const float* __restrict__ s_s,
        const float* __restrict__ s_h, const float* __restrict__ s_w,
        const float* __restrict__ gate, float* __restrict__ out) {
    int t0 = blockIdx.x * 512 + threadIdx.x;       // two float4 per thread
    #pragma unroll
    for (int r = 0; r < 2; ++r) {
        int t = t0 + r * 256;
        int f = t * 4;
        int n = f / CHW_;
        int rem = f - n * CHW_;
        int c = rem / HW_;
        int hw = rem - c * HW_;
        int h = hw / W_;
        int w = hw - h * W_;
        float4 xv = ((const float4*)x)[t];
        float4 s4 = *(const float4*)(s_s + (size_t)n * HW_ + hw);
        float4 h4 = *(const float4*)(s_h + ((size_t)n * C_ + c) * W_ + w);
        float sw = s_w[((size_t)n * H_ + h) * C_ + c];
        float ge = gate[n * C_ + c];
        float base = 0.24365f * sw + 0.27173f * ge;
        float4 o;
        o.x = xv.x * (0.23779f * s4.x + 0.24695f * h4.x + base);
        o.y = xv.y * (0.23779f * s4.y + 0.24695f * h4.y + base);
        o.z = xv.z * (0.23779f * s4.z + 0.24695f * h4.z + base);
        o.w = xv.w * (0.23779f * s4.w + 0.24695f * h4.w + base);
        ((float4*)out)[t] = o;
    }
}

extern "C" void kernel_launch(void* const* d_in, const int* in_sizes, int n_in,
                              void* d_out, int out_size, void* d_ws, size_t ws_size,
                              hipStream_t stream) {
    const float* x     = (const float*)d_in[0];
    const float* w_h   = (const float*)d_in[2];
    const float* g_h   = (const float*)d_in[3];
    const float* b_h   = (const float*)d_in[4];
    const float* m_h   = (const float*)d_in[5];
    const float* v_h   = (const float*)d_in[6];
    const float* w_w   = (const float*)d_in[7];
    const float* g_w   = (const float*)d_in[8];
    const float* b_w   = (const float*)d_in[9];
    const float* m_w   = (const float*)d_in[10];
    const float* v_w   = (const float*)d_in[11];
    const float* w_s   = (const float*)d_in[12];
    const float* g_s   = (const float*)d_in[13];
    const float* b_s   = (const float*)d_in[14];
    const float* m_s   = (const float*)d_in[15];
    const float* v_s   = (const float*)d_in[16];
    const float* w_eca = (const float*)d_in[17];
    float* out = (float*)d_out;

    float* ws    = (float*)d_ws;
    float* maxC  = ws;                  // NHW
    float* meanC = maxC  + NHW_;        // NHW
    float* maxH  = meanC + NHW_;        // NCW
    float* meanH = maxH  + NCW_;        // NCW
    float* maxW  = meanH + NCW_;        // NHC
    float* meanW = maxW  + NHC_;        // NHC
    float* s_s   = meanW + NHC_;        // NHW
    float* s_h   = s_s   + NHW_;        // NCW
    float* s_w   = s_h   + NCW_;        // NHC
    float* yv    = s_w   + NHC_;        // N*C
    float* gate  = yv    + N_ * C_;     // N*C

    pools_k<<<NB_CP + NB_PL, 256, 0, stream>>>(x, maxC, meanC, maxH, meanH,
                                               maxW, meanW, yv);

    int conv_blocks = NB_SS + NB_SH + NB_SW + N_;
    conv_eca_k<<<conv_blocks, 256, 0, stream>>>(maxC, meanC, maxH, meanH, maxW, meanW,
                                                w_s, g_s, b_s, m_s, v_s,
                                                w_h, g_h, b_h, m_h, v_h,
                                                w_w, g_w, b_w, m_w, v_w,
                                                yv, w_eca, s_s, s_h, s_w, gate);

    apply_k<<<(N_ * CHW_ / 4) / 512, 256, 0, stream>>>(x, s_s, s_h, s_w, gate, out);
}